// Round 8
// baseline (30.627 us; speedup 1.0000x reference)
//
#include <hip/hip_runtime.h>
#include <math.h>

#define BB 2
#define CC 16
#define HH 32
#define WW 32
#define NN (HH*WW)
#define NPX (BB*NN)        // 2048 pixels

// SoA k-record arrays:
//   E0..E3 : float4[NPX]  embedding e[0..15]
//   Q0     : float4[NPX]  X, Y, Z, p0   (unprojected xyz; p*=pie(T_k x_k)+rev)
//   Q1     : float4[NPX]  p1, p2, w0, w1
//   Q2     : float2[NPX]  w2, |e|^2

// ---------------------------------------------------------------------------
// Kernel 1: per-(b,k) precompute into SoA arrays (coalesced writes).
// ---------------------------------------------------------------------------
__global__ __launch_bounds__(64)
void dse3_prep6(const float* __restrict__ emb,
                const float* __restrict__ rev,
                const float* __restrict__ wgt,
                const float* __restrict__ dep,
                const float* __restrict__ pix,
                const float* __restrict__ Tm,
                float4* __restrict__ soa4,
                float2* __restrict__ soa2)
{
    int idx = blockIdx.x * 64 + threadIdx.x;
    if (idx >= NPX) return;
    int b = idx >> 10;
    int k = idx & (NN - 1);

    float fx = pix[b*16 + 0], fy = pix[b*16 + 5];
    float x0 = pix[b*16 + 2], y0 = pix[b*16 + 6];

    float u = (float)(k & (WW - 1));
    float v = (float)(k >> 5);
    float z = dep[b*NN + k];
    float X = (u - x0) * z / fx;
    float Y = (v - y0) * z / fy;

    const float* T = Tm + (size_t)idx * 16;
    float Tx = T[0]*X + T[1]*Y + T[2]*z  + T[3];
    float Ty = T[4]*X + T[5]*Y + T[6]*z  + T[7];
    float Tz = T[8]*X + T[9]*Y + T[10]*z + T[11];
    float di = 1.0f / Tz;

    float p0 = fx*Tx*di + x0 + rev[(size_t)b*3*NN + 0*NN + k];
    float p1 = fy*Ty*di + y0 + rev[(size_t)b*3*NN + 1*NN + k];
    float p2 = di            + rev[(size_t)b*3*NN + 2*NN + k];
    float w0 = wgt[(size_t)b*3*NN + 0*NN + k];
    float w1 = wgt[(size_t)b*3*NN + 1*NN + k];
    float w2 = wgt[(size_t)b*3*NN + 2*NN + k];

    float se = 0.f;
    float ev[16];
    #pragma unroll
    for (int c = 0; c < 16; ++c) {
        ev[c] = emb[(size_t)b*CC*NN + (size_t)c*NN + k];
        se += ev[c]*ev[c];
    }

    #pragma unroll
    for (int c4 = 0; c4 < 4; ++c4)
        soa4[(size_t)c4*NPX + idx] =
            make_float4(ev[c4*4+0], ev[c4*4+1], ev[c4*4+2], ev[c4*4+3]);
    soa4[(size_t)4*NPX + idx] = make_float4(X, Y, z, p0);
    soa4[(size_t)5*NPX + idx] = make_float4(p1, p2, w0, w1);
    soa2[idx] = make_float2(w2, se);
}

// ---------------------------------------------------------------------------
// Kernel 2 (fused): block = 256 thr = 4 waves; wave w -> pixel px0+(w>>1),
// k-half (w&1). One pixel per wave (low VGPR); 8 coalesced iters x 64 lanes.
// M-factorized H accumulation: 26 accumulators
//   aM: m00,m02,m11,m12,m22   (H[0..2][0..2], H01==0)
//   aN: n00..n22              (H[0..2][3..5] = M*hat(x))
//   aP: p00,p01,p02,p11,p12,p22 (H[3..5][3..5] = hat^T*M*hat)
//   aR: r0..r5                (rhs)
// Butterfly-reduce, LDS combine halves, 2 solver threads per block.
// ---------------------------------------------------------------------------
__global__ __launch_bounds__(256, 4)
void dse3_fused3(const float4* __restrict__ soa4,
                 const float2* __restrict__ soa2,
                 const float* __restrict__ pix,
                 const float* __restrict__ Tm,
                 float* __restrict__ out)
{
    __shared__ float lds[4][26];
    int tid  = threadIdx.x;
    int lane = tid & 63;
    int wv   = tid >> 6;                    // wave 0..3
    int px   = blockIdx.x * 2 + (wv >> 1);  // this wave's pixel
    int kh   = wv & 1;                      // k-half
    int b    = px >> 10;

    const float4* E0 = soa4;
    const float4* E1 = soa4 + (size_t)1*NPX;
    const float4* E2 = soa4 + (size_t)2*NPX;
    const float4* E3 = soa4 + (size_t)3*NPX;
    const float4* Q0 = soa4 + (size_t)4*NPX;
    const float4* Q1 = soa4 + (size_t)5*NPX;
    const float2* Q2 = soa2;

    float fx = pix[b*16 + 0], fy = pix[b*16 + 5];
    float x0 = pix[b*16 + 2], y0 = pix[b*16 + 6];

    // per-pixel broadcast data
    float4 e0 = E0[px], e1 = E1[px], e2 = E2[px], e3 = E3[px];
    float  sei = Q2[px].y;
    const float* Ti = Tm + (size_t)px * 16;
    float R00=Ti[0], R01=Ti[1], R02=Ti[2],  t0=Ti[3];
    float R10=Ti[4], R11=Ti[5], R12=Ti[6],  t1=Ti[7];
    float R20=Ti[8], R21=Ti[9], R22=Ti[10], t2=Ti[11];

    float aM0=0.f, aM2=0.f, aM4=0.f, aM5=0.f, aM8=0.f;       // m00,m02,m11,m12,m22
    float aN0=0.f, aN1=0.f, aN2=0.f, aN3=0.f, aN4=0.f,
          aN5=0.f, aN6=0.f, aN7=0.f, aN8=0.f;                // n00..n22
    float aP0=0.f, aP1=0.f, aP2=0.f, aP3=0.f, aP4=0.f, aP5=0.f; // p00,p01,p02,p11,p12,p22
    float aR0=0.f, aR1=0.f, aR2=0.f, aR3=0.f, aR4=0.f, aR5=0.f;

    int kbase = b * NN + kh * (NN/2);
    #pragma unroll 2
    for (int j = 0; j < 8; ++j) {
        int kb = kbase + j*64 + lane;      // consecutive lanes -> consecutive k

        float4 k0 = E0[kb], k1 = E1[kb], k2 = E2[kb], k3 = E3[kb];
        float4 q0 = Q0[kb], q1 = Q1[kb];
        float2 q2 = Q2[kb];

        // affinity via Gram trick
        float d0 = k0.x*e0.x + k0.y*e0.y + k0.z*e0.z + k0.w*e0.w;
        float d1 = k1.x*e1.x + k1.y*e1.y + k1.z*e1.z + k1.w*e1.w;
        float d2 = k2.x*e2.x + k2.y*e2.y + k2.z*e2.z + k2.w*e2.w;
        float d3 = k3.x*e3.x + k3.y*e3.y + k3.z*e3.z + k3.w*e3.w;
        float dot = (d0 + d1) + (d2 + d3);
        float ssq = fmaxf(sei + q2.y - 2.f*dot, 0.f);
        float aff = __expf(-__builtin_amdgcn_sqrtf(ssq));

        float X = q0.x, Y = q0.y, Z = q0.z;
        float Tx = R00*X + R01*Y + R02*Z + t0;
        float Ty = R10*X + R11*Y + R12*Z + t1;
        float Tz = R20*X + R21*Y + R22*Z + t2;
        float di = __builtin_amdgcn_rcpf(Tz);

        float a =  fx*di;
        float e =  fy*di;
        float uu = a*Tx;
        float vv = e*Ty;
        float r0 = uu + x0 - q0.w;
        float r1 = vv + y0 - q1.x;
        float r2 = di      - q1.y;
        float c = -uu*di;
        float f = -vv*di;
        float g = -di*di;

        // rhs: y = Jp^T r ; aR[0..2] += y ; aR[3..5] += hat^T y
        float y0v = a*r0;
        float y1v = e*r1;
        float y2v = c*r0 + f*r1 + g*r2;
        aR0 += y0v; aR1 += y1v; aR2 += y2v;
        aR3 += Z*y1v - Y*y2v;
        aR4 += X*y2v - Z*y0v;
        aR5 += Y*y0v - X*y1v;

        // weighted M = Jp^T diag(aff*w) Jp   (M01 == 0 structurally)
        float w0 = aff*q1.z, w1 = aff*q1.w, w2 = aff*q2.x;
        float aw = w0*a, ew = w1*e;
        float m00 = aw*a, m02 = aw*c;
        float m11 = ew*e, m12 = ew*f;
        float m22 = w0*c*c + w1*f*f + w2*g*g;
        aM0 += m00; aM2 += m02; aM4 += m11; aM5 += m12; aM8 += m22;

        // N = M * hat(X,Y,Z)
        float n00 = -m02*Y;
        float n01 =  m02*X - m00*Z;
        float n02 =  m00*Y;
        float n10 =  m11*Z - m12*Y;
        float n11 =  m12*X;
        float n12 = -m11*X;
        float n20 =  m12*Z - m22*Y;
        float n21 =  m22*X - m02*Z;
        float n22 =  m02*Y - m12*X;
        aN0 += n00; aN1 += n01; aN2 += n02;
        aN3 += n10; aN4 += n11; aN5 += n12;
        aN6 += n20; aN7 += n21; aN8 += n22;

        // P = hat^T * N  (symmetric)
        aP0 += Z*n10 - Y*n20;
        aP1 += Z*n11 - Y*n21;
        aP2 += Z*n12 - Y*n22;
        aP3 += X*n21 - Z*n01;
        aP4 += X*n22 - Z*n02;
        aP5 += Y*n02 - X*n12;
    }

    // pack into array for reduction
    float acc[26] = { aM0,aM2,aM4,aM5,aM8,
                      aN0,aN1,aN2,aN3,aN4,aN5,aN6,aN7,aN8,
                      aP0,aP1,aP2,aP3,aP4,aP5,
                      aR0,aR1,aR2,aR3,aR4,aR5 };

    #pragma unroll
    for (int off = 32; off > 0; off >>= 1)
        #pragma unroll
        for (int t = 0; t < 26; ++t)
            acc[t] += __shfl_xor(acc[t], off, 64);

    if (lane == 0)
        #pragma unroll
        for (int t = 0; t < 26; ++t) lds[wv][t] = acc[t];
    __syncthreads();

    // ---- 2 solver threads per block (tid 0 -> slot 0, tid 128 -> slot 1) ----
    if ((tid & 127) != 0) return;
    int s = tid >> 7;
    int opx = blockIdx.x * 2 + s;

    float hv[26];
    #pragma unroll
    for (int t = 0; t < 26; ++t) hv[t] = lds[2*s][t] + lds[2*s+1][t];

    // reconstruct H (6x6 symmetric), rhs
    float am[6][6];
    am[0][0]=hv[0]; am[0][1]=0.f;   am[0][2]=hv[1];
    am[1][1]=hv[2]; am[1][2]=hv[3]; am[2][2]=hv[4];
    am[0][3]=hv[5];  am[0][4]=hv[6];  am[0][5]=hv[7];
    am[1][3]=hv[8];  am[1][4]=hv[9];  am[1][5]=hv[10];
    am[2][3]=hv[11]; am[2][4]=hv[12]; am[2][5]=hv[13];
    am[3][3]=hv[14]; am[3][4]=hv[15]; am[3][5]=hv[16];
    am[4][4]=hv[17]; am[4][5]=hv[18]; am[5][5]=hv[19];
    #pragma unroll
    for (int p = 0; p < 6; ++p)
        #pragma unroll
        for (int q = 0; q < p; ++q) am[p][q] = am[q][p];
    float rh[6] = { hv[20], hv[21], hv[22], hv[23], hv[24], hv[25] };

    // f32 Cholesky
    float L[6][6];
    #pragma unroll
    for (int p = 0; p < 6; ++p) {
        #pragma unroll
        for (int q = 0; q <= p; ++q) {
            float sm = am[p][q];
            #pragma unroll
            for (int r = 0; r < q; ++r) sm -= L[p][r]*L[q][r];
            if (q == p) L[p][p] = sqrtf(sm);
            else        L[p][q] = sm / L[q][q];
        }
    }
    float yv[6];
    #pragma unroll
    for (int p = 0; p < 6; ++p) {
        float sm = rh[p];
        #pragma unroll
        for (int r = 0; r < p; ++r) sm -= L[p][r]*yv[r];
        yv[p] = sm / L[p][p];
    }
    float sol[6];
    #pragma unroll
    for (int pi = 5; pi >= 0; --pi) {
        float sm = yv[pi];
        #pragma unroll
        for (int r = pi + 1; r < 6; ++r) sm -= L[r][pi]*sol[r];
        sol[pi] = sm / L[pi][pi];
    }

    // expmap(delta)
    float vx = sol[0], vy = sol[1], vz = sol[2];
    float wx = sol[3], wy = sol[4], wz = sol[5];
    float th2 = wx*wx + wy*wy + wz*wz;
    float th  = sqrtf(th2);
    float Ae, Be, Ce;
    if (th < 1e-4f) {
        Ae = 1.0f - th2*(1.0f/6.0f);
        Be = 0.5f - th2*(1.0f/24.0f);
        Ce = 1.0f/6.0f - th2*(1.0f/120.0f);
    } else {
        float sn = __sinf(th), cn = __cosf(th);
        float ith = 1.0f/th, ith2 = ith*ith;
        Ae = sn*ith;
        Be = (1.0f - cn)*ith2;
        Ce = (th - sn)*ith2*ith;
    }
    float Wh[3][3] = {{0.f,-wz, wy},{ wz,0.f,-wx},{-wy, wx,0.f}};
    float W2[3][3] = {{wx*wx - th2, wx*wy,       wx*wz      },
                      {wx*wy,       wy*wy - th2, wy*wz      },
                      {wx*wz,       wy*wz,       wz*wz - th2}};
    float Rd[3][3], Vd[3][3];
    #pragma unroll
    for (int p = 0; p < 3; ++p)
        #pragma unroll
        for (int q = 0; q < 3; ++q) {
            float idq = (p == q) ? 1.0f : 0.0f;
            Rd[p][q] = idq + Ae*Wh[p][q] + Be*W2[p][q];
            Vd[p][q] = idq + Be*Wh[p][q] + Ce*W2[p][q];
        }
    float td[3];
    #pragma unroll
    for (int p = 0; p < 3; ++p)
        td[p] = Vd[p][0]*vx + Vd[p][1]*vy + Vd[p][2]*vz;

    const float* Tp = Tm + (size_t)opx * 16;
    float* o = out + (size_t)opx * 16;
    #pragma unroll
    for (int p = 0; p < 3; ++p) {
        #pragma unroll
        for (int q = 0; q < 4; ++q) {
            float sm = Rd[p][0]*Tp[q]
                     + Rd[p][1]*Tp[4 + q]
                     + Rd[p][2]*Tp[8 + q]
                     + td[p]   *Tp[12 + q];
            o[p*4 + q] = sm;
        }
    }
    #pragma unroll
    for (int q = 0; q < 4; ++q) o[12 + q] = Tp[12 + q];
}

extern "C" void kernel_launch(void* const* d_in, const int* in_sizes, int n_in,
                              void* d_out, int out_size, void* d_ws, size_t ws_size,
                              hipStream_t stream) {
    const float* emb = (const float*)d_in[0];  // (B,C,H,W)
    const float* rev = (const float*)d_in[1];  // (B,3,H,W)
    const float* wgt = (const float*)d_in[2];  // (B,3,H,W)
    const float* dep = (const float*)d_in[3];  // (B,1,H,W)
    const float* pix = (const float*)d_in[4];  // (B,4,4)
    const float* Tm  = (const float*)d_in[5];  // (B,H,W,4,4)
    float* out = (float*)d_out;                // (B,H,W,4,4)

    float4* soa4 = (float4*)d_ws;                      // 6*NPX float4 = 196 KB
    float2* soa2 = (float2*)(soa4 + (size_t)6*NPX);    // NPX float2   =  16 KB

    dse3_prep6 <<<NPX/64, 64, 0, stream>>>(emb, rev, wgt, dep, pix, Tm, soa4, soa2);
    dse3_fused3<<<NPX/2, 256, 0, stream>>>(soa4, soa2, pix, Tm, out);
}

// Round 9
// 30.515 us; speedup vs baseline: 1.0037x; 1.0037x over previous
//
#include <hip/hip_runtime.h>
#include <math.h>

#define BB 2
#define CC 16
#define HH 32
#define WW 32
#define NN (HH*WW)
#define NPX (BB*NN)        // 2048 pixels

// SoA k-record arrays:
//   E0..E3 : float4[NPX]  embedding e[0..15]
//   Q0     : float4[NPX]  X, Y, Z, p0   (unprojected xyz; p*=pie(T_k x_k)+rev)
//   Q1     : float4[NPX]  p1, p2, w0, w1
//   Q2     : float2[NPX]  w2, |e|^2

// ---------------------------------------------------------------------------
// Kernel 1: per-(b,k) precompute into SoA arrays (coalesced writes).
// ---------------------------------------------------------------------------
__global__ __launch_bounds__(64)
void dse3_prep6(const float* __restrict__ emb,
                const float* __restrict__ rev,
                const float* __restrict__ wgt,
                const float* __restrict__ dep,
                const float* __restrict__ pix,
                const float* __restrict__ Tm,
                float4* __restrict__ soa4,
                float2* __restrict__ soa2)
{
    int idx = blockIdx.x * 64 + threadIdx.x;
    if (idx >= NPX) return;
    int b = idx >> 10;
    int k = idx & (NN - 1);

    float fx = pix[b*16 + 0], fy = pix[b*16 + 5];
    float x0 = pix[b*16 + 2], y0 = pix[b*16 + 6];

    float u = (float)(k & (WW - 1));
    float v = (float)(k >> 5);
    float z = dep[b*NN + k];
    float X = (u - x0) * z / fx;
    float Y = (v - y0) * z / fy;

    const float* T = Tm + (size_t)idx * 16;
    float Tx = T[0]*X + T[1]*Y + T[2]*z  + T[3];
    float Ty = T[4]*X + T[5]*Y + T[6]*z  + T[7];
    float Tz = T[8]*X + T[9]*Y + T[10]*z + T[11];
    float di = 1.0f / Tz;

    float p0 = fx*Tx*di + x0 + rev[(size_t)b*3*NN + 0*NN + k];
    float p1 = fy*Ty*di + y0 + rev[(size_t)b*3*NN + 1*NN + k];
    float p2 = di            + rev[(size_t)b*3*NN + 2*NN + k];
    float w0 = wgt[(size_t)b*3*NN + 0*NN + k];
    float w1 = wgt[(size_t)b*3*NN + 1*NN + k];
    float w2 = wgt[(size_t)b*3*NN + 2*NN + k];

    float se = 0.f;
    float ev[16];
    #pragma unroll
    for (int c = 0; c < 16; ++c) {
        ev[c] = emb[(size_t)b*CC*NN + (size_t)c*NN + k];
        se += ev[c]*ev[c];
    }

    #pragma unroll
    for (int c4 = 0; c4 < 4; ++c4)
        soa4[(size_t)c4*NPX + idx] =
            make_float4(ev[c4*4+0], ev[c4*4+1], ev[c4*4+2], ev[c4*4+3]);
    soa4[(size_t)4*NPX + idx] = make_float4(X, Y, z, p0);
    soa4[(size_t)5*NPX + idx] = make_float4(p1, p2, w0, w1);
    soa2[idx] = make_float2(w2, se);
}

// ---------------------------------------------------------------------------
// Kernel 2 (fused): block = 256 thr = 4 waves; wave w -> pixel px0+(w>>1),
// k-half (w&1). One pixel per wave (low VGPR); 8 coalesced iters x 64 lanes.
// M-factorized H accumulation: 26 accumulators
//   aM: m00,m02,m11,m12,m22   (H[0..2][0..2], H01==0)
//   aN: n00..n22              (H[0..2][3..5] = M*hat(x))
//   aP: p00,p01,p02,p11,p12,p22 (H[3..5][3..5] = hat^T*M*hat)
//   aR: r0..r5                (rhs)
// Butterfly-reduce, LDS combine halves, 2 solver threads per block.
// ---------------------------------------------------------------------------
__global__ __launch_bounds__(256, 4)
void dse3_fused3(const float4* __restrict__ soa4,
                 const float2* __restrict__ soa2,
                 const float* __restrict__ pix,
                 const float* __restrict__ Tm,
                 float* __restrict__ out)
{
    __shared__ float lds[4][26];
    int tid  = threadIdx.x;
    int lane = tid & 63;
    int wv   = tid >> 6;                    // wave 0..3
    int px   = blockIdx.x * 2 + (wv >> 1);  // this wave's pixel
    int kh   = wv & 1;                      // k-half
    int b    = px >> 10;

    const float4* E0 = soa4;
    const float4* E1 = soa4 + (size_t)1*NPX;
    const float4* E2 = soa4 + (size_t)2*NPX;
    const float4* E3 = soa4 + (size_t)3*NPX;
    const float4* Q0 = soa4 + (size_t)4*NPX;
    const float4* Q1 = soa4 + (size_t)5*NPX;
    const float2* Q2 = soa2;

    float fx = pix[b*16 + 0], fy = pix[b*16 + 5];
    float x0 = pix[b*16 + 2], y0 = pix[b*16 + 6];

    // per-pixel broadcast data
    float4 e0 = E0[px], e1 = E1[px], e2 = E2[px], e3 = E3[px];
    float  sei = Q2[px].y;
    const float* Ti = Tm + (size_t)px * 16;
    float R00=Ti[0], R01=Ti[1], R02=Ti[2],  t0=Ti[3];
    float R10=Ti[4], R11=Ti[5], R12=Ti[6],  t1=Ti[7];
    float R20=Ti[8], R21=Ti[9], R22=Ti[10], t2=Ti[11];

    float aM0=0.f, aM2=0.f, aM4=0.f, aM5=0.f, aM8=0.f;       // m00,m02,m11,m12,m22
    float aN0=0.f, aN1=0.f, aN2=0.f, aN3=0.f, aN4=0.f,
          aN5=0.f, aN6=0.f, aN7=0.f, aN8=0.f;                // n00..n22
    float aP0=0.f, aP1=0.f, aP2=0.f, aP3=0.f, aP4=0.f, aP5=0.f; // p00,p01,p02,p11,p12,p22
    float aR0=0.f, aR1=0.f, aR2=0.f, aR3=0.f, aR4=0.f, aR5=0.f;

    int kbase = b * NN + kh * (NN/2);
    #pragma unroll 2
    for (int j = 0; j < 8; ++j) {
        int kb = kbase + j*64 + lane;      // consecutive lanes -> consecutive k

        float4 k0 = E0[kb], k1 = E1[kb], k2 = E2[kb], k3 = E3[kb];
        float4 q0 = Q0[kb], q1 = Q1[kb];
        float2 q2 = Q2[kb];

        // affinity via Gram trick
        float d0 = k0.x*e0.x + k0.y*e0.y + k0.z*e0.z + k0.w*e0.w;
        float d1 = k1.x*e1.x + k1.y*e1.y + k1.z*e1.z + k1.w*e1.w;
        float d2 = k2.x*e2.x + k2.y*e2.y + k2.z*e2.z + k2.w*e2.w;
        float d3 = k3.x*e3.x + k3.y*e3.y + k3.z*e3.z + k3.w*e3.w;
        float dot = (d0 + d1) + (d2 + d3);
        float ssq = fmaxf(sei + q2.y - 2.f*dot, 0.f);
        float aff = __expf(-__builtin_amdgcn_sqrtf(ssq));

        float X = q0.x, Y = q0.y, Z = q0.z;
        float Tx = R00*X + R01*Y + R02*Z + t0;
        float Ty = R10*X + R11*Y + R12*Z + t1;
        float Tz = R20*X + R21*Y + R22*Z + t2;
        float di = __builtin_amdgcn_rcpf(Tz);

        float a =  fx*di;
        float e =  fy*di;
        float uu = a*Tx;
        float vv = e*Ty;
        float r0 = uu + x0 - q0.w;
        float r1 = vv + y0 - q1.x;
        float r2 = di      - q1.y;
        float c = -uu*di;
        float f = -vv*di;
        float g = -di*di;

        // rhs: y = Jp^T r ; aR[0..2] += y ; aR[3..5] += hat^T y
        float y0v = a*r0;
        float y1v = e*r1;
        float y2v = c*r0 + f*r1 + g*r2;
        aR0 += y0v; aR1 += y1v; aR2 += y2v;
        aR3 += Z*y1v - Y*y2v;
        aR4 += X*y2v - Z*y0v;
        aR5 += Y*y0v - X*y1v;

        // weighted M = Jp^T diag(aff*w) Jp   (M01 == 0 structurally)
        float w0 = aff*q1.z, w1 = aff*q1.w, w2 = aff*q2.x;
        float aw = w0*a, ew = w1*e;
        float m00 = aw*a, m02 = aw*c;
        float m11 = ew*e, m12 = ew*f;
        float m22 = w0*c*c + w1*f*f + w2*g*g;
        aM0 += m00; aM2 += m02; aM4 += m11; aM5 += m12; aM8 += m22;

        // N = M * hat(X,Y,Z)
        float n00 = -m02*Y;
        float n01 =  m02*X - m00*Z;
        float n02 =  m00*Y;
        float n10 =  m11*Z - m12*Y;
        float n11 =  m12*X;
        float n12 = -m11*X;
        float n20 =  m12*Z - m22*Y;
        float n21 =  m22*X - m02*Z;
        float n22 =  m02*Y - m12*X;
        aN0 += n00; aN1 += n01; aN2 += n02;
        aN3 += n10; aN4 += n11; aN5 += n12;
        aN6 += n20; aN7 += n21; aN8 += n22;

        // P = hat^T * N  (symmetric)
        aP0 += Z*n10 - Y*n20;
        aP1 += Z*n11 - Y*n21;
        aP2 += Z*n12 - Y*n22;
        aP3 += X*n21 - Z*n01;
        aP4 += X*n22 - Z*n02;
        aP5 += Y*n02 - X*n12;
    }

    // pack into array for reduction
    float acc[26] = { aM0,aM2,aM4,aM5,aM8,
                      aN0,aN1,aN2,aN3,aN4,aN5,aN6,aN7,aN8,
                      aP0,aP1,aP2,aP3,aP4,aP5,
                      aR0,aR1,aR2,aR3,aR4,aR5 };

    #pragma unroll
    for (int off = 32; off > 0; off >>= 1)
        #pragma unroll
        for (int t = 0; t < 26; ++t)
            acc[t] += __shfl_xor(acc[t], off, 64);

    if (lane == 0)
        #pragma unroll
        for (int t = 0; t < 26; ++t) lds[wv][t] = acc[t];
    __syncthreads();

    // ---- 2 solver threads per block (tid 0 -> slot 0, tid 128 -> slot 1) ----
    if ((tid & 127) != 0) return;
    int s = tid >> 7;
    int opx = blockIdx.x * 2 + s;

    float hv[26];
    #pragma unroll
    for (int t = 0; t < 26; ++t) hv[t] = lds[2*s][t] + lds[2*s+1][t];

    // reconstruct H (6x6 symmetric), rhs
    float am[6][6];
    am[0][0]=hv[0]; am[0][1]=0.f;   am[0][2]=hv[1];
    am[1][1]=hv[2]; am[1][2]=hv[3]; am[2][2]=hv[4];
    am[0][3]=hv[5];  am[0][4]=hv[6];  am[0][5]=hv[7];
    am[1][3]=hv[8];  am[1][4]=hv[9];  am[1][5]=hv[10];
    am[2][3]=hv[11]; am[2][4]=hv[12]; am[2][5]=hv[13];
    am[3][3]=hv[14]; am[3][4]=hv[15]; am[3][5]=hv[16];
    am[4][4]=hv[17]; am[4][5]=hv[18]; am[5][5]=hv[19];
    #pragma unroll
    for (int p = 0; p < 6; ++p)
        #pragma unroll
        for (int q = 0; q < p; ++q) am[p][q] = am[q][p];
    float rh[6] = { hv[20], hv[21], hv[22], hv[23], hv[24], hv[25] };

    // f32 Cholesky
    float L[6][6];
    #pragma unroll
    for (int p = 0; p < 6; ++p) {
        #pragma unroll
        for (int q = 0; q <= p; ++q) {
            float sm = am[p][q];
            #pragma unroll
            for (int r = 0; r < q; ++r) sm -= L[p][r]*L[q][r];
            if (q == p) L[p][p] = sqrtf(sm);
            else        L[p][q] = sm / L[q][q];
        }
    }
    float yv[6];
    #pragma unroll
    for (int p = 0; p < 6; ++p) {
        float sm = rh[p];
        #pragma unroll
        for (int r = 0; r < p; ++r) sm -= L[p][r]*yv[r];
        yv[p] = sm / L[p][p];
    }
    float sol[6];
    #pragma unroll
    for (int pi = 5; pi >= 0; --pi) {
        float sm = yv[pi];
        #pragma unroll
        for (int r = pi + 1; r < 6; ++r) sm -= L[r][pi]*sol[r];
        sol[pi] = sm / L[pi][pi];
    }

    // expmap(delta)
    float vx = sol[0], vy = sol[1], vz = sol[2];
    float wx = sol[3], wy = sol[4], wz = sol[5];
    float th2 = wx*wx + wy*wy + wz*wz;
    float th  = sqrtf(th2);
    float Ae, Be, Ce;
    if (th < 1e-4f) {
        Ae = 1.0f - th2*(1.0f/6.0f);
        Be = 0.5f - th2*(1.0f/24.0f);
        Ce = 1.0f/6.0f - th2*(1.0f/120.0f);
    } else {
        float sn = __sinf(th), cn = __cosf(th);
        float ith = 1.0f/th, ith2 = ith*ith;
        Ae = sn*ith;
        Be = (1.0f - cn)*ith2;
        Ce = (th - sn)*ith2*ith;
    }
    float Wh[3][3] = {{0.f,-wz, wy},{ wz,0.f,-wx},{-wy, wx,0.f}};
    float W2[3][3] = {{wx*wx - th2, wx*wy,       wx*wz      },
                      {wx*wy,       wy*wy - th2, wy*wz      },
                      {wx*wz,       wy*wz,       wz*wz - th2}};
    float Rd[3][3], Vd[3][3];
    #pragma unroll
    for (int p = 0; p < 3; ++p)
        #pragma unroll
        for (int q = 0; q < 3; ++q) {
            float idq = (p == q) ? 1.0f : 0.0f;
            Rd[p][q] = idq + Ae*Wh[p][q] + Be*W2[p][q];
            Vd[p][q] = idq + Be*Wh[p][q] + Ce*W2[p][q];
        }
    float td[3];
    #pragma unroll
    for (int p = 0; p < 3; ++p)
        td[p] = Vd[p][0]*vx + Vd[p][1]*vy + Vd[p][2]*vz;

    const float* Tp = Tm + (size_t)opx * 16;
    float* o = out + (size_t)opx * 16;
    #pragma unroll
    for (int p = 0; p < 3; ++p) {
        #pragma unroll
        for (int q = 0; q < 4; ++q) {
            float sm = Rd[p][0]*Tp[q]
                     + Rd[p][1]*Tp[4 + q]
                     + Rd[p][2]*Tp[8 + q]
                     + td[p]   *Tp[12 + q];
            o[p*4 + q] = sm;
        }
    }
    #pragma unroll
    for (int q = 0; q < 4; ++q) o[12 + q] = Tp[12 + q];
}

extern "C" void kernel_launch(void* const* d_in, const int* in_sizes, int n_in,
                              void* d_out, int out_size, void* d_ws, size_t ws_size,
                              hipStream_t stream) {
    const float* emb = (const float*)d_in[0];  // (B,C,H,W)
    const float* rev = (const float*)d_in[1];  // (B,3,H,W)
    const float* wgt = (const float*)d_in[2];  // (B,3,H,W)
    const float* dep = (const float*)d_in[3];  // (B,1,H,W)
    const float* pix = (const float*)d_in[4];  // (B,4,4)
    const float* Tm  = (const float*)d_in[5];  // (B,H,W,4,4)
    float* out = (float*)d_out;                // (B,H,W,4,4)

    float4* soa4 = (float4*)d_ws;                      // 6*NPX float4 = 196 KB
    float2* soa2 = (float2*)(soa4 + (size_t)6*NPX);    // NPX float2   =  16 KB

    dse3_prep6 <<<NPX/64, 64, 0, stream>>>(emb, rev, wgt, dep, pix, Tm, soa4, soa2);
    dse3_fused3<<<NPX/2, 256, 0, stream>>>(soa4, soa2, pix, Tm, out);
}